// Round 10
// baseline (82.685 us; speedup 1.0000x reference)
//
#include <hip/hip_runtime.h>
#include <math.h>

#define kB 4
#define kM 4096
#define kN (kB * kM)
#define kPadF -999.0f
#define kPadI -999

// numpy-mimicking squared norm: (x*x + y*y) + z*z, all round-to-nearest,
// no fma contraction (np.sum over axis -1 of cb*cb).
__device__ __forceinline__ float sq_np(float x, float y, float z) {
    return __fadd_rn(__fadd_rn(__fmul_rn(x, x), __fmul_rn(y, y)),
                     __fmul_rn(z, z));
}

// raw v_sqrt_f32 (approx, <=1 ulp). The inclusion mask is decided by the
// exact d2<=49 compare, so sqrt value error only perturbs the sum ~1e-6.
__device__ __forceinline__ float fast_sqrt(float x) {
#if __has_builtin(__builtin_amdgcn_sqrtf)
    return __builtin_amdgcn_sqrtf(x);
#else
    float r;
    asm volatile("v_sqrt_f32 %0, %1" : "=v"(r) : "v"(x));
    return r;
#endif
}

// ---------------------------------------------------------------------------
// Kernel 1: per-atom outputs — dihedral (col 0), partners (cols 2..7) —
// plus pre-gather of (x, y, z, sq) into ws, and col-1 = 0 init (the
// symmetric nbr kernel accumulates atomically on top of it).
// ---------------------------------------------------------------------------
__global__ __launch_bounds__(64)
void per_atom_kernel(const float* __restrict__ coords,   // (B,M,3)
                     const int*   __restrict__ cidx,     // (N,)
                     const int*   __restrict__ partners, // (N,2)
                     const int*   __restrict__ aidx,     // (N,4)
                     float*       __restrict__ out,      // (N,8)
                     float4*      __restrict__ ws)       // (N,) gathered
{
    int i = blockIdx.x * 64 + threadIdx.x;
    if (i >= kN) return;
    int b = i >> 12;  // atom_batch = i // M, M = 4096

    // ---- pre-gather for nbr kernel: x, y, z, sq (numpy rounding) ----
    {
        int gc = cidx[i];
        const float* s = coords + (size_t)(b * kM + gc) * 3;
        float x = s[0], y = s[1], z = s[2];
        ws[i] = make_float4(x, y, z, sq_np(x, y, z));
    }

    // ---- partners (cols 2..7) ----
    float o2, o3, o4, o5, o6, o7;
    int p0 = partners[2 * i + 0];
    int p1 = partners[2 * i + 1];
    if (p0 == kPadI) { o2 = o3 = o4 = kPadF; }
    else {
        const float* s = coords + (size_t)(b * kM + p0) * 3;
        o2 = s[0]; o3 = s[1]; o4 = s[2];
    }
    if (p1 == kPadI) { o5 = o6 = o7 = kPadF; }
    else {
        const float* s = coords + (size_t)(b * kM + p1) * 3;
        o5 = s[0]; o6 = s[1]; o7 = s[2];
    }

    // ---- dihedral (col 0) ----
    int4 a = *reinterpret_cast<const int4*>(aidx + 4 * i);
    float ang = kPadF;
    if (a.x != kPadI && a.y != kPadI && a.z != kPadI && a.w != kPadI) {
        int ai[4] = {a.x, a.y, a.z, a.w};
        float P[4][3];
        #pragma unroll
        for (int k = 0; k < 4; ++k) {
            int g  = ai[k];
            int gb = g >> 12;
            int gc = cidx[g];
            const float* s = coords + (size_t)(gb * kM + gc) * 3;
            P[k][0] = s[0]; P[k][1] = s[1]; P[k][2] = s[2];
        }
        float b1x = P[1][0] - P[0][0], b1y = P[1][1] - P[0][1], b1z = P[1][2] - P[0][2];
        float b2x = P[2][0] - P[1][0], b2y = P[2][1] - P[1][1], b2z = P[2][2] - P[1][2];
        float b3x = P[3][0] - P[2][0], b3y = P[3][1] - P[2][1], b3z = P[3][2] - P[2][2];
        float n1x = b1y * b2z - b1z * b2y;
        float n1y = b1z * b2x - b1x * b2z;
        float n1z = b1x * b2y - b1y * b2x;
        float n2x = b2y * b3z - b2z * b3y;
        float n2y = b2z * b3x - b2x * b3z;
        float n2z = b2x * b3y - b2y * b3x;
        float nb2 = sqrtf(b2x * b2x + b2y * b2y + b2z * b2z) + 1e-12f;
        float inv = 1.0f / nb2;
        float ux = b2x * inv, uy = b2y * inv, uz = b2z * inv;
        float m1x = n1y * uz - n1z * uy;
        float m1y = n1z * ux - n1x * uz;
        float m1z = n1x * uy - n1y * ux;
        float x = n1x * n2x + n1y * n2y + n1z * n2z;
        float y = m1x * n2x + m1y * n2y + m1z * n2z;
        ang = atan2f(y, x);
    }

    float4* o = reinterpret_cast<float4*>(out + (size_t)i * 8);
    o[0] = make_float4(ang, 0.0f, o2, o3);   // col 1 = 0, accumulated later
    o[1] = make_float4(o4, o5, o6, o7);
}

// ---------------------------------------------------------------------------
// Kernel 2: SYMMETRIC masked pairwise-distance row sums (col 1).
// dist(i,j) is bitwise-symmetric in the reference's rounding (dot and
// sq_i+sq_j commutative-identical), so only the upper triangle of 256x256
// tiles is computed: 136 tiles/batch (16 diag full + 120 off-diag credited
// to BOTH row-sums (regs) and col-sums (LDS atomics, rare-lane only)).
// PAD HANDLING (pads are SCATTERED rows: row i is pad iff cidx[i] lands in
// the padded region — R7 lesson): pad x = -999 bitwise, so
//   valid x pad  : dx >= 999  -> d2 >= ~1e6, self-excluded by d2<=49.
//   pad x pad    : dx == 0, CAN be within cutoff -> must be dropped:
//                  row-write guarded by ri.x != pad, col-flush guarded by
//                  sc[tid].x != pad (the R7 bug: this guard was missing).
// Mask is exact without sqrt: dist<=7 <=> d2<=49.0f; sqrt only under a
// wave-uniform __any branch (~16% of col-iters).
// ---------------------------------------------------------------------------
__global__ __launch_bounds__(256)
void nbr_sym_kernel(const float4* __restrict__ ws,  // (N,) x,y,z,sq
                    float*        __restrict__ out) // (N,8)
{
    __shared__ float4 sc[256];      // column tile
    __shared__ float  colsum[256];  // column partial sums

    // unrank block -> (batch, tile-row, tile-col), upper triangle incl diag
    int blk = blockIdx.x;
    int b   = blk / 136;
    int t   = blk - b * 136;
    int tr  = 0;
    while (t >= 16 - tr) { t -= 16 - tr; ++tr; }
    int tc  = tr + t;
    bool diag = (tc == tr);

    const float4* base = ws + (size_t)b * kM;
    int tid = threadIdx.x;

    sc[tid]     = base[tc * 256 + tid];
    colsum[tid] = 0.0f;
    float4 ri   = base[tr * 256 + tid];
    __syncthreads();

    float rowsum = 0.0f;
    for (int j = 0; j < 256; j += 4) {
        float4 cc0 = sc[j + 0], cc1 = sc[j + 1], cc2 = sc[j + 2], cc3 = sc[j + 3];
        #pragma unroll
        for (int u = 0; u < 4; ++u) {
            float4 c = (u == 0) ? cc0 : (u == 1) ? cc1 : (u == 2) ? cc2 : cc3;
            float dot = __fmaf_rn(ri.z, c.z,
                        __fmaf_rn(ri.y, c.y, __fmul_rn(ri.x, c.x)));
            // d2 = (sq_i + sq_j) - 2*dot  (fma form bit-identical: -2*dot exact)
            float d2  = __fmaf_rn(-2.0f, dot, __fadd_rn(ri.w, c.w));
            bool  in  = (d2 <= 49.0f);
            if (__any(in)) {   // wave-uniform scalar branch
                float dist = fast_sqrt(__fadd_rn(fmaxf(d2, 0.0f), 1e-12f));
                rowsum += in ? dist : 0.0f;
                if (!diag && in) {              // ~1 active lane typical
                    atomicAdd(&colsum[j + u], dist);
                }
            }
        }
    }
    __syncthreads();

    if (ri.x != kPadF && rowsum != 0.0f) {
        atomicAdd(out + (size_t)(b * kM + tr * 256 + tid) * 8 + 1, rowsum);
    }
    if (!diag) {
        float cs = colsum[tid];
        // column-validity guard: drops pad-pad credits (R7 bugfix)
        if (cs != 0.0f && sc[tid].x != kPadF) {
            atomicAdd(out + (size_t)(b * kM + tc * 256 + tid) * 8 + 1, cs);
        }
    }
}

// ---------------------------------------------------------------------------
// Fallback (ws too small): self-contained full (asymmetric) nbr kernel.
// ---------------------------------------------------------------------------
__global__ __launch_bounds__(256)
void nbr_kernel_lds(const float* __restrict__ coords,
                    const int*   __restrict__ cidx,
                    float*       __restrict__ out)
{
    __shared__ float4 sc[kM];
    int b    = blockIdx.x >> 6;
    int row0 = (blockIdx.x & 63) << 6;
    for (int j = threadIdx.x; j < kM; j += 256) {
        int idx = cidx[b * kM + j];
        const float* s = coords + (size_t)(b * kM + idx) * 3;
        float x = s[0], y = s[1], z = s[2];
        sc[j] = make_float4(x, y, z, sq_np(x, y, z));
    }
    __syncthreads();
    int r   = row0 + (threadIdx.x >> 2);
    int sub = threadIdx.x & 3;
    float4 ci = sc[r];
    float sum = 0.0f;
    for (int jj = 0; jj < kM / 4; ++jj) {
        float4 c   = sc[4 * jj + sub];
        float dot  = __fmaf_rn(ci.z, c.z,
                     __fmaf_rn(ci.y, c.y, __fmul_rn(ci.x, c.x)));
        float d2   = __fmaf_rn(-2.0f, dot, __fadd_rn(ci.w, c.w));
        bool  in   = (d2 <= 49.0f);
        if (__any(in)) {
            float dist = fast_sqrt(__fadd_rn(fmaxf(d2, 0.0f), 1e-12f));
            sum += in ? dist : 0.0f;
        }
    }
    sum += __shfl_xor(sum, 1);
    sum += __shfl_xor(sum, 2);
    if (sub == 0)
        out[(size_t)(b * kM + r) * 8 + 1] = (ci.x != kPadF) ? sum : 0.0f;
}

// ---------------------------------------------------------------------------
extern "C" void kernel_launch(void* const* d_in, const int* in_sizes, int n_in,
                              void* d_out, int out_size, void* d_ws, size_t ws_size,
                              hipStream_t stream) {
    const float* coords   = (const float*)d_in[0];
    const int*   cidx     = (const int*)d_in[2];
    const int*   partners = (const int*)d_in[3];
    const int*   aidx     = (const int*)d_in[4];
    float*       out      = (float*)d_out;
    float4*      ws       = (float4*)d_ws;

    hipLaunchKernelGGL(per_atom_kernel, dim3(kN / 64), dim3(64), 0, stream,
                       coords, cidx, partners, aidx, out, ws);

    if (ws_size >= (size_t)kN * sizeof(float4)) {
        hipLaunchKernelGGL(nbr_sym_kernel, dim3(kB * 136), dim3(256), 0, stream,
                           ws, out);
    } else {
        hipLaunchKernelGGL(nbr_kernel_lds, dim3(kB * 64), dim3(256), 0, stream,
                           coords, cidx, out);
    }
}

// Round 11
// 82.183 us; speedup vs baseline: 1.0061x; 1.0061x over previous
//
#include <hip/hip_runtime.h>
#include <math.h>

#define kB 4
#define kM 4096
#define kN (kB * kM)
#define kPadF -999.0f
#define kPadI -999

// numpy-mimicking squared norm: (x*x + y*y) + z*z, all round-to-nearest,
// no fma contraction (np.sum over axis -1 of cb*cb).
__device__ __forceinline__ float sq_np(float x, float y, float z) {
    return __fadd_rn(__fadd_rn(__fmul_rn(x, x), __fmul_rn(y, y)),
                     __fmul_rn(z, z));
}

// raw v_sqrt_f32 (approx, <=1 ulp). The inclusion mask is decided by the
// exact d2<=49 compare, so sqrt value error only perturbs the sum ~1e-6.
__device__ __forceinline__ float fast_sqrt(float x) {
#if __has_builtin(__builtin_amdgcn_sqrtf)
    return __builtin_amdgcn_sqrtf(x);
#else
    float r;
    asm volatile("v_sqrt_f32 %0, %1" : "=v"(r) : "v"(x));
    return r;
#endif
}

// ---------------------------------------------------------------------------
// Kernel 1: per-atom outputs — dihedral (col 0), partners (cols 2..7) —
// plus pre-gather of (x, y, z, sq) into ws, and col-1 = 0 init (the
// symmetric nbr kernel accumulates atomically on top of it).
// ---------------------------------------------------------------------------
__global__ __launch_bounds__(64)
void per_atom_kernel(const float* __restrict__ coords,   // (B,M,3)
                     const int*   __restrict__ cidx,     // (N,)
                     const int*   __restrict__ partners, // (N,2)
                     const int*   __restrict__ aidx,     // (N,4)
                     float*       __restrict__ out,      // (N,8)
                     float4*      __restrict__ ws)       // (N,) gathered
{
    int i = blockIdx.x * 64 + threadIdx.x;
    if (i >= kN) return;
    int b = i >> 12;  // atom_batch = i // M, M = 4096

    // ---- pre-gather for nbr kernel: x, y, z, sq (numpy rounding) ----
    {
        int gc = cidx[i];
        const float* s = coords + (size_t)(b * kM + gc) * 3;
        float x = s[0], y = s[1], z = s[2];
        ws[i] = make_float4(x, y, z, sq_np(x, y, z));
    }

    // ---- partners (cols 2..7) ----
    float o2, o3, o4, o5, o6, o7;
    int p0 = partners[2 * i + 0];
    int p1 = partners[2 * i + 1];
    if (p0 == kPadI) { o2 = o3 = o4 = kPadF; }
    else {
        const float* s = coords + (size_t)(b * kM + p0) * 3;
        o2 = s[0]; o3 = s[1]; o4 = s[2];
    }
    if (p1 == kPadI) { o5 = o6 = o7 = kPadF; }
    else {
        const float* s = coords + (size_t)(b * kM + p1) * 3;
        o5 = s[0]; o6 = s[1]; o7 = s[2];
    }

    // ---- dihedral (col 0) ----
    int4 a = *reinterpret_cast<const int4*>(aidx + 4 * i);
    float ang = kPadF;
    if (a.x != kPadI && a.y != kPadI && a.z != kPadI && a.w != kPadI) {
        int ai[4] = {a.x, a.y, a.z, a.w};
        float P[4][3];
        #pragma unroll
        for (int k = 0; k < 4; ++k) {
            int g  = ai[k];
            int gb = g >> 12;
            int gc = cidx[g];
            const float* s = coords + (size_t)(gb * kM + gc) * 3;
            P[k][0] = s[0]; P[k][1] = s[1]; P[k][2] = s[2];
        }
        float b1x = P[1][0] - P[0][0], b1y = P[1][1] - P[0][1], b1z = P[1][2] - P[0][2];
        float b2x = P[2][0] - P[1][0], b2y = P[2][1] - P[1][1], b2z = P[2][2] - P[1][2];
        float b3x = P[3][0] - P[2][0], b3y = P[3][1] - P[2][1], b3z = P[3][2] - P[2][2];
        float n1x = b1y * b2z - b1z * b2y;
        float n1y = b1z * b2x - b1x * b2z;
        float n1z = b1x * b2y - b1y * b2x;
        float n2x = b2y * b3z - b2z * b3y;
        float n2y = b2z * b3x - b2x * b3z;
        float n2z = b2x * b3y - b2y * b3x;
        float nb2 = sqrtf(b2x * b2x + b2y * b2y + b2z * b2z) + 1e-12f;
        float inv = 1.0f / nb2;
        float ux = b2x * inv, uy = b2y * inv, uz = b2z * inv;
        float m1x = n1y * uz - n1z * uy;
        float m1y = n1z * ux - n1x * uz;
        float m1z = n1x * uy - n1y * ux;
        float x = n1x * n2x + n1y * n2y + n1z * n2z;
        float y = m1x * n2x + m1y * n2y + m1z * n2z;
        ang = atan2f(y, x);
    }

    float4* o = reinterpret_cast<float4*>(out + (size_t)i * 8);
    o[0] = make_float4(ang, 0.0f, o2, o3);   // col 1 = 0, accumulated later
    o[1] = make_float4(o4, o5, o6, o7);
}

// ---------------------------------------------------------------------------
// Kernel 2: SYMMETRIC pairwise-distance sums, v2 (R11):
//  - row path BRANCHLESS with raw v_sqrt (R5 lesson: OCML sqrt was the 100-cyc
//    poison, not branchlessness; mask stays the exact d2<=49.0f compare)
//  - __any branch retained ONLY for the off-diag colsum LDS atomic
//  - occupancy: each 256x256 tile split into 2 column halves ->
//    grid = B * 136 * 2 = 1088 blocks (4.25/CU), 256 thr, 1 row/thread,
//    128 cols in LDS.
// PAD HANDLING (R7 lesson: pads are scattered rows): valid x pad pairs
// self-exclude (d2 ~ 1e6); pad x pad pairs can pass the cutoff -> dropped by
// validity guards on BOTH the rowsum write and the colsum flush.
// ---------------------------------------------------------------------------
__global__ __launch_bounds__(256)
void nbr_sym_kernel(const float4* __restrict__ ws,  // (N,) x,y,z,sq
                    float*        __restrict__ out) // (N,8)
{
    __shared__ float4 sc[128];      // column half-tile
    __shared__ float  colsum[128];  // column partial sums

    // unrank block -> (batch, tile-row, tile-col, col-half)
    int blk  = blockIdx.x;
    int half = blk & 1;
    int bt   = blk >> 1;            // 0..543
    int b    = bt / 136;
    int t    = bt - b * 136;
    int tr   = 0;
    while (t >= 16 - tr) { t -= 16 - tr; ++tr; }
    int tc   = tr + t;
    bool diag = (tc == tr);

    const float4* base = ws + (size_t)b * kM;
    int tid = threadIdx.x;

    if (tid < 128) {
        sc[tid]     = base[tc * 256 + half * 128 + tid];
        colsum[tid] = 0.0f;
    }
    float4 ri = base[tr * 256 + tid];   // this thread's row
    __syncthreads();

    float rowsum = 0.0f;
    for (int j = 0; j < 128; j += 4) {
        float4 cc0 = sc[j + 0], cc1 = sc[j + 1], cc2 = sc[j + 2], cc3 = sc[j + 3];
        #pragma unroll
        for (int u = 0; u < 4; ++u) {
            float4 c = (u == 0) ? cc0 : (u == 1) ? cc1 : (u == 2) ? cc2 : cc3;
            float dot = __fmaf_rn(ri.z, c.z,
                        __fmaf_rn(ri.y, c.y, __fmul_rn(ri.x, c.x)));
            // d2 = (sq_i + sq_j) - 2*dot  (fma form bit-identical: -2*dot exact)
            float d2   = __fmaf_rn(-2.0f, dot, __fadd_rn(ri.w, c.w));
            // value: sqrt(max(d2,0)); skipping +1e-12 shifts dist <=1e-10,
            // and v_sqrt is 1-ulp (<=1e-6 per term) — mask below is exact.
            float dist = fast_sqrt(fmaxf(d2, 0.0f));
            bool  in   = (d2 <= 49.0f);
            rowsum += in ? dist : 0.0f;          // cndmask+add, no branch
            if (!diag) {                          // block-uniform
                if (__any(in)) {                  // rare (~16%), tiny body
                    if (in) atomicAdd(&colsum[j + u], dist);
                }
            }
        }
    }
    __syncthreads();

    if (ri.x != kPadF && rowsum != 0.0f) {
        atomicAdd(out + (size_t)(b * kM + tr * 256 + tid) * 8 + 1, rowsum);
    }
    if (!diag && tid < 128) {
        float cs = colsum[tid];
        // column-validity guard: drops pad-pad credits (R7 bugfix)
        if (cs != 0.0f && sc[tid].x != kPadF) {
            atomicAdd(out + (size_t)(b * kM + tc * 256 + half * 128 + tid) * 8 + 1, cs);
        }
    }
}

// ---------------------------------------------------------------------------
// Fallback (ws too small): self-contained full (asymmetric) nbr kernel.
// ---------------------------------------------------------------------------
__global__ __launch_bounds__(256)
void nbr_kernel_lds(const float* __restrict__ coords,
                    const int*   __restrict__ cidx,
                    float*       __restrict__ out)
{
    __shared__ float4 sc[kM];
    int b    = blockIdx.x >> 6;
    int row0 = (blockIdx.x & 63) << 6;
    for (int j = threadIdx.x; j < kM; j += 256) {
        int idx = cidx[b * kM + j];
        const float* s = coords + (size_t)(b * kM + idx) * 3;
        float x = s[0], y = s[1], z = s[2];
        sc[j] = make_float4(x, y, z, sq_np(x, y, z));
    }
    __syncthreads();
    int r   = row0 + (threadIdx.x >> 2);
    int sub = threadIdx.x & 3;
    float4 ci = sc[r];
    float sum = 0.0f;
    for (int jj = 0; jj < kM / 4; ++jj) {
        float4 c   = sc[4 * jj + sub];
        float dot  = __fmaf_rn(ci.z, c.z,
                     __fmaf_rn(ci.y, c.y, __fmul_rn(ci.x, c.x)));
        float d2   = __fmaf_rn(-2.0f, dot, __fadd_rn(ci.w, c.w));
        float dist = fast_sqrt(fmaxf(d2, 0.0f));
        sum += (d2 <= 49.0f) ? dist : 0.0f;
    }
    sum += __shfl_xor(sum, 1);
    sum += __shfl_xor(sum, 2);
    if (sub == 0)
        out[(size_t)(b * kM + r) * 8 + 1] = (ci.x != kPadF) ? sum : 0.0f;
}

// ---------------------------------------------------------------------------
extern "C" void kernel_launch(void* const* d_in, const int* in_sizes, int n_in,
                              void* d_out, int out_size, void* d_ws, size_t ws_size,
                              hipStream_t stream) {
    const float* coords   = (const float*)d_in[0];
    const int*   cidx     = (const int*)d_in[2];
    const int*   partners = (const int*)d_in[3];
    const int*   aidx     = (const int*)d_in[4];
    float*       out      = (float*)d_out;
    float4*      ws       = (float4*)d_ws;

    hipLaunchKernelGGL(per_atom_kernel, dim3(kN / 64), dim3(64), 0, stream,
                       coords, cidx, partners, aidx, out, ws);

    if (ws_size >= (size_t)kN * sizeof(float4)) {
        hipLaunchKernelGGL(nbr_sym_kernel, dim3(kB * 136 * 2), dim3(256), 0, stream,
                           ws, out);
    } else {
        hipLaunchKernelGGL(nbr_kernel_lds, dim3(kB * 64), dim3(256), 0, stream,
                           coords, cidx, out);
    }
}

// Round 12
// 81.486 us; speedup vs baseline: 1.0147x; 1.0085x over previous
//
#include <hip/hip_runtime.h>
#include <math.h>

#define kB 4
#define kM 4096
#define kN (kB * kM)
#define kPadF -999.0f
#define kPadI -999

// numpy-mimicking squared norm: (x*x + y*y) + z*z, all round-to-nearest,
// no fma contraction (np.sum over axis -1 of cb*cb).
__device__ __forceinline__ float sq_np(float x, float y, float z) {
    return __fadd_rn(__fadd_rn(__fmul_rn(x, x), __fmul_rn(y, y)),
                     __fmul_rn(z, z));
}

// raw v_sqrt_f32 (approx, <=1 ulp). The inclusion mask is decided by the
// exact d2<=49 compare, so sqrt value error only perturbs the sum ~1e-6.
__device__ __forceinline__ float fast_sqrt(float x) {
#if __has_builtin(__builtin_amdgcn_sqrtf)
    return __builtin_amdgcn_sqrtf(x);
#else
    float r;
    asm volatile("v_sqrt_f32 %0, %1" : "=v"(r) : "v"(x));
    return r;
#endif
}

// ---------------------------------------------------------------------------
// Kernel 1: per-atom outputs — dihedral (col 0), partners (cols 2..7) —
// plus pre-gather of (x, y, z, sq) into ws, and col-1 = 0 init (nbr
// accumulates atomically on top of it).
// ---------------------------------------------------------------------------
__global__ __launch_bounds__(64)
void per_atom_kernel(const float* __restrict__ coords,   // (B,M,3)
                     const int*   __restrict__ cidx,     // (N,)
                     const int*   __restrict__ partners, // (N,2)
                     const int*   __restrict__ aidx,     // (N,4)
                     float*       __restrict__ out,      // (N,8)
                     float4*      __restrict__ ws)       // (N,) gathered
{
    int i = blockIdx.x * 64 + threadIdx.x;
    if (i >= kN) return;
    int b = i >> 12;  // atom_batch = i // M, M = 4096

    // ---- pre-gather for nbr kernel: x, y, z, sq (numpy rounding) ----
    {
        int gc = cidx[i];
        const float* s = coords + (size_t)(b * kM + gc) * 3;
        float x = s[0], y = s[1], z = s[2];
        ws[i] = make_float4(x, y, z, sq_np(x, y, z));
    }

    // ---- partners (cols 2..7) ----
    float o2, o3, o4, o5, o6, o7;
    int p0 = partners[2 * i + 0];
    int p1 = partners[2 * i + 1];
    if (p0 == kPadI) { o2 = o3 = o4 = kPadF; }
    else {
        const float* s = coords + (size_t)(b * kM + p0) * 3;
        o2 = s[0]; o3 = s[1]; o4 = s[2];
    }
    if (p1 == kPadI) { o5 = o6 = o7 = kPadF; }
    else {
        const float* s = coords + (size_t)(b * kM + p1) * 3;
        o5 = s[0]; o6 = s[1]; o7 = s[2];
    }

    // ---- dihedral (col 0) ----
    int4 a = *reinterpret_cast<const int4*>(aidx + 4 * i);
    float ang = kPadF;
    if (a.x != kPadI && a.y != kPadI && a.z != kPadI && a.w != kPadI) {
        int ai[4] = {a.x, a.y, a.z, a.w};
        float P[4][3];
        #pragma unroll
        for (int k = 0; k < 4; ++k) {
            int g  = ai[k];
            int gb = g >> 12;
            int gc = cidx[g];
            const float* s = coords + (size_t)(gb * kM + gc) * 3;
            P[k][0] = s[0]; P[k][1] = s[1]; P[k][2] = s[2];
        }
        float b1x = P[1][0] - P[0][0], b1y = P[1][1] - P[0][1], b1z = P[1][2] - P[0][2];
        float b2x = P[2][0] - P[1][0], b2y = P[2][1] - P[1][1], b2z = P[2][2] - P[1][2];
        float b3x = P[3][0] - P[2][0], b3y = P[3][1] - P[2][1], b3z = P[3][2] - P[2][2];
        float n1x = b1y * b2z - b1z * b2y;
        float n1y = b1z * b2x - b1x * b2z;
        float n1z = b1x * b2y - b1y * b2x;
        float n2x = b2y * b3z - b2z * b3y;
        float n2y = b2z * b3x - b2x * b3z;
        float n2z = b2x * b3y - b2y * b3x;
        float nb2 = sqrtf(b2x * b2x + b2y * b2y + b2z * b2z) + 1e-12f;
        float inv = 1.0f / nb2;
        float ux = b2x * inv, uy = b2y * inv, uz = b2z * inv;
        float m1x = n1y * uz - n1z * uy;
        float m1y = n1z * ux - n1x * uz;
        float m1z = n1x * uy - n1y * ux;
        float x = n1x * n2x + n1y * n2y + n1z * n2z;
        float y = m1x * n2x + m1y * n2y + m1z * n2z;
        ang = atan2f(y, x);
    }

    float4* o = reinterpret_cast<float4*>(out + (size_t)i * 8);
    o[0] = make_float4(ang, 0.0f, o2, o3);   // col 1 = 0, accumulated later
    o[1] = make_float4(o4, o5, o6, o7);
}

// ---------------------------------------------------------------------------
// Kernel 2: FULL-SQUARE pairwise-distance row sums (col 1), v3 (R12):
// occupancy probe — 8 blocks/CU (32 waves/CU), ZERO branches in the hot
// loop (no __any, no colsum, no symmetry), raw v_sqrt always.
// Grid 2048 = 16 row-blocks (1024 rows, 4/thread) x 128 col-chunks (32 cols
// in 512B LDS). Atomic row-credit at end, filtered by sum!=0 (~8% taken).
// Numerics identical to R11's absmax-0.5 path:
//   dot  = fma(z, fma(y, mul(x)));  d2 = fma(-2, dot, sqi+sqj)
//   dist = v_sqrt(max(d2,0));       mask d2 <= 49.0f exact.
// Pad rows: write-guarded. Pad cols: self-excluded (d2 ~ 1e6) except
// pad-pad, which only pad ROWS see -> killed by the row write-guard.
// ---------------------------------------------------------------------------
__global__ __launch_bounds__(256, 8)
void nbr_full_kernel(const float4* __restrict__ ws,  // (N,) x,y,z,sq
                     float*        __restrict__ out) // (N,8)
{
    __shared__ float4 sc[32];       // column chunk

    int rowBlk = blockIdx.x >> 7;   // 0..15  (1024 rows each)
    int colChk = blockIdx.x & 127;  // 0..127 (32 cols each)
    int row0   = rowBlk << 10;
    int b      = rowBlk >> 2;       // 4 row-blocks per batch
    int col0   = colChk << 5;

    int tid = threadIdx.x;
    if (tid < 32) sc[tid] = ws[(size_t)b * kM + col0 + tid];

    // 4 rows per thread: row0 + tid + k*256
    float rx[4], ry[4], rz[4], rsq[4], sum[4];
    bool  rv[4];
    #pragma unroll
    for (int k = 0; k < 4; ++k) {
        float4 ci = ws[row0 + tid + (k << 8)];
        rx[k] = ci.x; ry[k] = ci.y; rz[k] = ci.z; rsq[k] = ci.w;
        rv[k] = (ci.x != kPadF);
        sum[k] = 0.0f;
    }
    __syncthreads();

    #pragma unroll 2
    for (int j = 0; j < 32; j += 4) {
        float4 cc0 = sc[j + 0], cc1 = sc[j + 1], cc2 = sc[j + 2], cc3 = sc[j + 3];
        #pragma unroll
        for (int u = 0; u < 4; ++u) {
            float4 c = (u == 0) ? cc0 : (u == 1) ? cc1 : (u == 2) ? cc2 : cc3;
            #pragma unroll
            for (int k = 0; k < 4; ++k) {
                float dot  = __fmaf_rn(rz[k], c.z,
                             __fmaf_rn(ry[k], c.y, __fmul_rn(rx[k], c.x)));
                float d2   = __fmaf_rn(-2.0f, dot, __fadd_rn(rsq[k], c.w));
                float dist = fast_sqrt(fmaxf(d2, 0.0f));
                sum[k] += (d2 <= 49.0f) ? dist : 0.0f;   // cndmask+add
            }
        }
    }

    #pragma unroll
    for (int k = 0; k < 4; ++k) {
        if (rv[k] && sum[k] != 0.0f) {
            atomicAdd(out + (size_t)(row0 + tid + (k << 8)) * 8 + 1, sum[k]);
        }
    }
}

// ---------------------------------------------------------------------------
// Fallback (ws too small): self-contained full (asymmetric) nbr kernel.
// ---------------------------------------------------------------------------
__global__ __launch_bounds__(256)
void nbr_kernel_lds(const float* __restrict__ coords,
                    const int*   __restrict__ cidx,
                    float*       __restrict__ out)
{
    __shared__ float4 sc[kM];
    int b    = blockIdx.x >> 6;
    int row0 = (blockIdx.x & 63) << 6;
    for (int j = threadIdx.x; j < kM; j += 256) {
        int idx = cidx[b * kM + j];
        const float* s = coords + (size_t)(b * kM + idx) * 3;
        float x = s[0], y = s[1], z = s[2];
        sc[j] = make_float4(x, y, z, sq_np(x, y, z));
    }
    __syncthreads();
    int r   = row0 + (threadIdx.x >> 2);
    int sub = threadIdx.x & 3;
    float4 ci = sc[r];
    float sum = 0.0f;
    for (int jj = 0; jj < kM / 4; ++jj) {
        float4 c   = sc[4 * jj + sub];
        float dot  = __fmaf_rn(ci.z, c.z,
                     __fmaf_rn(ci.y, c.y, __fmul_rn(ci.x, c.x)));
        float d2   = __fmaf_rn(-2.0f, dot, __fadd_rn(ci.w, c.w));
        float dist = fast_sqrt(fmaxf(d2, 0.0f));
        sum += (d2 <= 49.0f) ? dist : 0.0f;
    }
    sum += __shfl_xor(sum, 1);
    sum += __shfl_xor(sum, 2);
    if (sub == 0)
        out[(size_t)(b * kM + r) * 8 + 1] = (ci.x != kPadF) ? sum : 0.0f;
}

// ---------------------------------------------------------------------------
extern "C" void kernel_launch(void* const* d_in, const int* in_sizes, int n_in,
                              void* d_out, int out_size, void* d_ws, size_t ws_size,
                              hipStream_t stream) {
    const float* coords   = (const float*)d_in[0];
    const int*   cidx     = (const int*)d_in[2];
    const int*   partners = (const int*)d_in[3];
    const int*   aidx     = (const int*)d_in[4];
    float*       out      = (float*)d_out;
    float4*      ws       = (float4*)d_ws;

    hipLaunchKernelGGL(per_atom_kernel, dim3(kN / 64), dim3(64), 0, stream,
                       coords, cidx, partners, aidx, out, ws);

    if (ws_size >= (size_t)kN * sizeof(float4)) {
        hipLaunchKernelGGL(nbr_full_kernel, dim3(2048), dim3(256), 0, stream,
                           ws, out);
    } else {
        hipLaunchKernelGGL(nbr_kernel_lds, dim3(kB * 64), dim3(256), 0, stream,
                           coords, cidx, out);
    }
}

// Round 13
// 79.304 us; speedup vs baseline: 1.0426x; 1.0275x over previous
//
#include <hip/hip_runtime.h>
#include <math.h>

#define kB 4
#define kM 4096
#define kN (kB * kM)
#define kPadF -999.0f
#define kPadI -999

typedef float f32x2 __attribute__((ext_vector_type(2)));

// numpy-mimicking squared norm: (x*x + y*y) + z*z, all round-to-nearest.
__device__ __forceinline__ float sq_np(float x, float y, float z) {
    return __fadd_rn(__fadd_rn(__fmul_rn(x, x), __fmul_rn(y, y)),
                     __fmul_rn(z, z));
}

// raw v_sqrt_f32 (<=1 ulp). Mask is decided by the exact d2<=49 compare.
__device__ __forceinline__ float fast_sqrt(float x) {
#if __has_builtin(__builtin_amdgcn_sqrtf)
    return __builtin_amdgcn_sqrtf(x);
#else
    float r;
    asm volatile("v_sqrt_f32 %0, %1" : "=v"(r) : "v"(x));
    return r;
#endif
}

// dual-issue packed f32 (CDNA VOP3P) — hipcc never auto-emits these.
__device__ __forceinline__ f32x2 pk_mul(f32x2 a, f32x2 b) {
    f32x2 d;
    asm("v_pk_mul_f32 %0, %1, %2" : "=v"(d) : "v"(a), "v"(b));
    return d;
}
__device__ __forceinline__ f32x2 pk_fma(f32x2 a, f32x2 b, f32x2 c) {
    f32x2 d;
    asm("v_pk_fma_f32 %0, %1, %2, %3" : "=v"(d) : "v"(a), "v"(b), "v"(c));
    return d;
}
__device__ __forceinline__ f32x2 pk_add(f32x2 a, f32x2 b) {
    f32x2 d;
    asm("v_pk_add_f32 %0, %1, %2" : "=v"(d) : "v"(a), "v"(b));
    return d;
}

// ---------------------------------------------------------------------------
// Kernel 1: per-atom outputs — dihedral (col 0), partners (cols 2..7) —
// plus pre-gather of (x, y, z, sq) into ws, and col-1 = 0 init.
// ---------------------------------------------------------------------------
__global__ __launch_bounds__(64)
void per_atom_kernel(const float* __restrict__ coords,   // (B,M,3)
                     const int*   __restrict__ cidx,     // (N,)
                     const int*   __restrict__ partners, // (N,2)
                     const int*   __restrict__ aidx,     // (N,4)
                     float*       __restrict__ out,      // (N,8)
                     float4*      __restrict__ ws)       // (N,) gathered
{
    int i = blockIdx.x * 64 + threadIdx.x;
    if (i >= kN) return;
    int b = i >> 12;

    {
        int gc = cidx[i];
        const float* s = coords + (size_t)(b * kM + gc) * 3;
        float x = s[0], y = s[1], z = s[2];
        ws[i] = make_float4(x, y, z, sq_np(x, y, z));
    }

    float o2, o3, o4, o5, o6, o7;
    int p0 = partners[2 * i + 0];
    int p1 = partners[2 * i + 1];
    if (p0 == kPadI) { o2 = o3 = o4 = kPadF; }
    else {
        const float* s = coords + (size_t)(b * kM + p0) * 3;
        o2 = s[0]; o3 = s[1]; o4 = s[2];
    }
    if (p1 == kPadI) { o5 = o6 = o7 = kPadF; }
    else {
        const float* s = coords + (size_t)(b * kM + p1) * 3;
        o5 = s[0]; o6 = s[1]; o7 = s[2];
    }

    int4 a = *reinterpret_cast<const int4*>(aidx + 4 * i);
    float ang = kPadF;
    if (a.x != kPadI && a.y != kPadI && a.z != kPadI && a.w != kPadI) {
        int ai[4] = {a.x, a.y, a.z, a.w};
        float P[4][3];
        #pragma unroll
        for (int k = 0; k < 4; ++k) {
            int g  = ai[k];
            int gb = g >> 12;
            int gc = cidx[g];
            const float* s = coords + (size_t)(gb * kM + gc) * 3;
            P[k][0] = s[0]; P[k][1] = s[1]; P[k][2] = s[2];
        }
        float b1x = P[1][0] - P[0][0], b1y = P[1][1] - P[0][1], b1z = P[1][2] - P[0][2];
        float b2x = P[2][0] - P[1][0], b2y = P[2][1] - P[1][1], b2z = P[2][2] - P[1][2];
        float b3x = P[3][0] - P[2][0], b3y = P[3][1] - P[2][1], b3z = P[3][2] - P[2][2];
        float n1x = b1y * b2z - b1z * b2y;
        float n1y = b1z * b2x - b1x * b2z;
        float n1z = b1x * b2y - b1y * b2x;
        float n2x = b2y * b3z - b2z * b3y;
        float n2y = b2z * b3x - b2x * b3z;
        float n2z = b2x * b3y - b2y * b3x;
        float nb2 = sqrtf(b2x * b2x + b2y * b2y + b2z * b2z) + 1e-12f;
        float inv = 1.0f / nb2;
        float ux = b2x * inv, uy = b2y * inv, uz = b2z * inv;
        float m1x = n1y * uz - n1z * uy;
        float m1y = n1z * ux - n1x * uz;
        float m1z = n1x * uy - n1y * ux;
        float x = n1x * n2x + n1y * n2y + n1z * n2z;
        float y = m1x * n2x + m1y * n2y + m1z * n2z;
        ang = atan2f(y, x);
    }

    float4* o = reinterpret_cast<float4*>(out + (size_t)i * 8);
    o[0] = make_float4(ang, 0.0f, o2, o3);
    o[1] = make_float4(o4, o5, o6, o7);
}

// ---------------------------------------------------------------------------
// Kernel 2: FULL-SQUARE branchless row sums, v4 (R13): packed-f32 core.
// Grid 2048 = 16 row-blocks (1024 rows, 4/thread) x 128 col-chunks (32 cols).
// LDS is SoA of f32x2 (column PAIRS per component) -> ds_read_b64 feeds
// v_pk_{mul,fma,add}_f32 directly (2 pairs per instruction, no packing movs).
// Mask path bit-identical per half to the proven absmax-0.5 numerics:
//   dot = fma(z,fma(y,mul(x))); t1 = rsq+c.w; d2 = fma(-2,dot,t1); d2<=49.
// sqrt(|d2|) replaces sqrt(max(d2,0)): differs only on self-pairs by <=3e-4.
// Pad rows write-guarded; pad cols self-exclude vs valid rows (d2~1e6);
// pad-pad pairs only seen by pad rows -> killed by the write guard.
// ---------------------------------------------------------------------------
__global__ __launch_bounds__(256, 4)
void nbr_pk_kernel(const float4* __restrict__ ws,  // (N,) x,y,z,sq
                   float*        __restrict__ out) // (N,8)
{
    __shared__ f32x2 sxx[16], syy[16], szz[16], sww[16];  // 32 cols SoA

    int rowBlk = blockIdx.x >> 7;   // 0..15  (1024 rows each)
    int colChk = blockIdx.x & 127;  // 0..127 (32 cols each)
    int row0   = rowBlk << 10;
    int b      = rowBlk >> 2;
    int col0   = colChk << 5;

    int tid = threadIdx.x;
    if (tid < 32) {
        float4 c = ws[(size_t)b * kM + col0 + tid];
        ((float*)sxx)[tid] = c.x;
        ((float*)syy)[tid] = c.y;
        ((float*)szz)[tid] = c.z;
        ((float*)sww)[tid] = c.w;
    }

    // 4 rows per thread: row0 + tid + k*256; duplicate row scalars into pairs
    f32x2 rxp[4], ryp[4], rzp[4], rqp[4];
    float s0[4], s1[4];
    bool  rv[4];
    #pragma unroll
    for (int k = 0; k < 4; ++k) {
        float4 ci = ws[row0 + tid + (k << 8)];
        rxp[k] = (f32x2){ci.x, ci.x};
        ryp[k] = (f32x2){ci.y, ci.y};
        rzp[k] = (f32x2){ci.z, ci.z};
        rqp[k] = (f32x2){ci.w, ci.w};
        rv[k]  = (ci.x != kPadF);
        s0[k] = 0.0f; s1[k] = 0.0f;
    }
    __syncthreads();

    #pragma unroll 4
    for (int j2 = 0; j2 < 16; ++j2) {
        f32x2 xp = sxx[j2], yp = syy[j2], zp = szz[j2], wp = sww[j2];
        #pragma unroll
        for (int k = 0; k < 4; ++k) {
            f32x2 dp  = pk_mul(rxp[k], xp);
            dp        = pk_fma(ryp[k], yp, dp);
            dp        = pk_fma(rzp[k], zp, dp);        // dot per half
            f32x2 t1  = pk_add(rqp[k], wp);            // sq_i + sq_j
            f32x2 d2  = pk_fma((f32x2){-2.0f, -2.0f}, dp, t1);
            float dist0 = fast_sqrt(__builtin_fabsf(d2[0]));  // |.| = free mod
            float dist1 = fast_sqrt(__builtin_fabsf(d2[1]));
            s0[k] += (d2[0] <= 49.0f) ? dist0 : 0.0f;
            s1[k] += (d2[1] <= 49.0f) ? dist1 : 0.0f;
        }
    }

    #pragma unroll
    for (int k = 0; k < 4; ++k) {
        float sum = s0[k] + s1[k];
        if (rv[k] && sum != 0.0f) {
            atomicAdd(out + (size_t)(row0 + tid + (k << 8)) * 8 + 1, sum);
        }
    }
}

// ---------------------------------------------------------------------------
// Fallback (ws too small): self-contained full nbr kernel.
// ---------------------------------------------------------------------------
__global__ __launch_bounds__(256)
void nbr_kernel_lds(const float* __restrict__ coords,
                    const int*   __restrict__ cidx,
                    float*       __restrict__ out)
{
    __shared__ float4 sc[kM];
    int b    = blockIdx.x >> 6;
    int row0 = (blockIdx.x & 63) << 6;
    for (int j = threadIdx.x; j < kM; j += 256) {
        int idx = cidx[b * kM + j];
        const float* s = coords + (size_t)(b * kM + idx) * 3;
        float x = s[0], y = s[1], z = s[2];
        sc[j] = make_float4(x, y, z, sq_np(x, y, z));
    }
    __syncthreads();
    int r   = row0 + (threadIdx.x >> 2);
    int sub = threadIdx.x & 3;
    float4 ci = sc[r];
    float sum = 0.0f;
    for (int jj = 0; jj < kM / 4; ++jj) {
        float4 c   = sc[4 * jj + sub];
        float dot  = __fmaf_rn(ci.z, c.z,
                     __fmaf_rn(ci.y, c.y, __fmul_rn(ci.x, c.x)));
        float d2   = __fmaf_rn(-2.0f, dot, __fadd_rn(ci.w, c.w));
        float dist = fast_sqrt(fmaxf(d2, 0.0f));
        sum += (d2 <= 49.0f) ? dist : 0.0f;
    }
    sum += __shfl_xor(sum, 1);
    sum += __shfl_xor(sum, 2);
    if (sub == 0)
        out[(size_t)(b * kM + r) * 8 + 1] = (ci.x != kPadF) ? sum : 0.0f;
}

// ---------------------------------------------------------------------------
extern "C" void kernel_launch(void* const* d_in, const int* in_sizes, int n_in,
                              void* d_out, int out_size, void* d_ws, size_t ws_size,
                              hipStream_t stream) {
    const float* coords   = (const float*)d_in[0];
    const int*   cidx     = (const int*)d_in[2];
    const int*   partners = (const int*)d_in[3];
    const int*   aidx     = (const int*)d_in[4];
    float*       out      = (float*)d_out;
    float4*      ws       = (float4*)d_ws;

    hipLaunchKernelGGL(per_atom_kernel, dim3(kN / 64), dim3(64), 0, stream,
                       coords, cidx, partners, aidx, out, ws);

    if (ws_size >= (size_t)kN * sizeof(float4)) {
        hipLaunchKernelGGL(nbr_pk_kernel, dim3(2048), dim3(256), 0, stream,
                           ws, out);
    } else {
        hipLaunchKernelGGL(nbr_kernel_lds, dim3(kB * 64), dim3(256), 0, stream,
                           coords, cidx, out);
    }
}

// Round 14
// 74.607 us; speedup vs baseline: 1.1083x; 1.0630x over previous
//
#include <hip/hip_runtime.h>
#include <math.h>

#define kB 4
#define kM 4096
#define kN (kB * kM)
#define kPadF -999.0f
#define kPadI -999

#define kNC   11                    // cells per axis; 80/11 = 7.27 > CUTOFF
#define kNC3  (kNC * kNC * kNC)     // 1331 cells per batch
#define kCap  64                    // atoms per cell (realistic max ~15)
// d_ws layout (bytes):
#define kOffWs     0                            // float4[kN]      = 256 KB
#define kOffCnt    262144                       // int[kB*kNC3]    = 21 KB
#define kOffCells  524288                       // float4[kB*kNC3*kCap] = 5.45 MB
#define kWsNeeded  (kOffCells + (size_t)kB * kNC3 * kCap * 16)

typedef float f32x2 __attribute__((ext_vector_type(2)));

// numpy-mimicking squared norm: (x*x + y*y) + z*z, all round-to-nearest.
__device__ __forceinline__ float sq_np(float x, float y, float z) {
    return __fadd_rn(__fadd_rn(__fmul_rn(x, x), __fmul_rn(y, y)),
                     __fmul_rn(z, z));
}

// raw v_sqrt_f32 (<=1 ulp). Mask is decided by the exact d2<=49 compare.
__device__ __forceinline__ float fast_sqrt(float x) {
#if __has_builtin(__builtin_amdgcn_sqrtf)
    return __builtin_amdgcn_sqrtf(x);
#else
    float r;
    asm volatile("v_sqrt_f32 %0, %1" : "=v"(r) : "v"(x));
    return r;
#endif
}

__device__ __forceinline__ int cell_coord(float v) {
    int c = (int)(v * (11.0f / 80.0f));
    return min(c, kNC - 1);        // x<80 guarantees c<=10; clamp for safety
}

// ---------------------------------------------------------------------------
// Kernel 1: per-atom outputs — dihedral (col 0), partners (cols 2..7),
// col-1 = 0 init — plus pre-gather of (x,y,z,sq) into ws AND cell binning
// (valid rows only) for the cell-list nbr kernel.
// ---------------------------------------------------------------------------
__global__ __launch_bounds__(64)
void per_atom_kernel(const float* __restrict__ coords,   // (B,M,3)
                     const int*   __restrict__ cidx,     // (N,)
                     const int*   __restrict__ partners, // (N,2)
                     const int*   __restrict__ aidx,     // (N,4)
                     float*       __restrict__ out,      // (N,8)
                     float4*      __restrict__ ws,       // gathered rows
                     int*         __restrict__ cellCnt,  // (B*1331,) zeroed
                     float4*      __restrict__ cells)    // (B*1331*kCap,)
{
    int i = blockIdx.x * 64 + threadIdx.x;
    if (i >= kN) return;
    int b = i >> 12;

    // ---- gather + bin ----
    {
        int gc = cidx[i];
        const float* s = coords + (size_t)(b * kM + gc) * 3;
        float x = s[0], y = s[1], z = s[2];
        float4 v = make_float4(x, y, z, sq_np(x, y, z));
        ws[i] = v;
        if (x != kPadF) {
            int cid = ((b * kNC + cell_coord(x)) * kNC + cell_coord(y)) * kNC
                      + cell_coord(z);
            int slot = atomicAdd(&cellCnt[cid], 1);
            if (slot < kCap) cells[(size_t)cid * kCap + slot] = v;
        }
    }

    // ---- partners (cols 2..7) ----
    float o2, o3, o4, o5, o6, o7;
    int p0 = partners[2 * i + 0];
    int p1 = partners[2 * i + 1];
    if (p0 == kPadI) { o2 = o3 = o4 = kPadF; }
    else {
        const float* s = coords + (size_t)(b * kM + p0) * 3;
        o2 = s[0]; o3 = s[1]; o4 = s[2];
    }
    if (p1 == kPadI) { o5 = o6 = o7 = kPadF; }
    else {
        const float* s = coords + (size_t)(b * kM + p1) * 3;
        o5 = s[0]; o6 = s[1]; o7 = s[2];
    }

    // ---- dihedral (col 0) ----
    int4 a = *reinterpret_cast<const int4*>(aidx + 4 * i);
    float ang = kPadF;
    if (a.x != kPadI && a.y != kPadI && a.z != kPadI && a.w != kPadI) {
        int ai[4] = {a.x, a.y, a.z, a.w};
        float P[4][3];
        #pragma unroll
        for (int k = 0; k < 4; ++k) {
            int g  = ai[k];
            int gb = g >> 12;
            int gc = cidx[g];
            const float* s = coords + (size_t)(gb * kM + gc) * 3;
            P[k][0] = s[0]; P[k][1] = s[1]; P[k][2] = s[2];
        }
        float b1x = P[1][0] - P[0][0], b1y = P[1][1] - P[0][1], b1z = P[1][2] - P[0][2];
        float b2x = P[2][0] - P[1][0], b2y = P[2][1] - P[1][1], b2z = P[2][2] - P[1][2];
        float b3x = P[3][0] - P[2][0], b3y = P[3][1] - P[2][1], b3z = P[3][2] - P[2][2];
        float n1x = b1y * b2z - b1z * b2y;
        float n1y = b1z * b2x - b1x * b2z;
        float n1z = b1x * b2y - b1y * b2x;
        float n2x = b2y * b3z - b2z * b3y;
        float n2y = b2z * b3x - b2x * b3z;
        float n2z = b2x * b3y - b2y * b3x;
        float nb2 = sqrtf(b2x * b2x + b2y * b2y + b2z * b2z) + 1e-12f;
        float inv = 1.0f / nb2;
        float ux = b2x * inv, uy = b2y * inv, uz = b2z * inv;
        float m1x = n1y * uz - n1z * uy;
        float m1y = n1z * ux - n1x * uz;
        float m1z = n1x * uy - n1y * ux;
        float x = n1x * n2x + n1y * n2y + n1z * n2z;
        float y = m1x * n2x + m1y * n2y + m1z * n2z;
        ang = atan2f(y, x);
    }

    float4* o = reinterpret_cast<float4*>(out + (size_t)i * 8);
    o[0] = make_float4(ang, 0.0f, o2, o3);   // col 1 = 0, accumulated later
    o[1] = make_float4(o4, o5, o6, o7);
}

// ---------------------------------------------------------------------------
// Kernel 2: CELL-LIST nbr sums (col 1). Task = (row i, neighbor cell k).
// 27*16384 tasks; k = task>>14, i = task&16383 (no division). Consecutive
// lanes = consecutive rows -> coalesced ws reads, 64-address atomics.
// Included-pair set and per-pair numerics are IDENTICAL to the R13 passing
// kernel: candidates beyond the 27-cell window have true dist >= 7.27 so
// gram-d2 >= ~52.8 > 49 — excluded by the mask anyway. Only the summation
// order differs (atomic), error ~1e-5 vs threshold 20.
// Pads never binned; pad rows return early (col1 stays 0 from per_atom).
// ---------------------------------------------------------------------------
__global__ __launch_bounds__(256)
void nbr_cell_kernel(const float4* __restrict__ ws,      // (N,) x,y,z,sq
                     const int*    __restrict__ cellCnt, // (B*1331,)
                     const float4* __restrict__ cells,   // (B*1331*kCap,)
                     float*        __restrict__ out)     // (N,8)
{
    int task = blockIdx.x * 256 + threadIdx.x;
    if (task >= 27 * kN) return;
    int k = task >> 14;            // 0..26  (kN = 16384 = 2^14)
    int i = task & (kN - 1);

    float4 ri = ws[i];
    if (ri.x == kPadF) return;

    int b  = i >> 12;
    int nx = cell_coord(ri.x) + (k / 9)     - 1;
    int ny = cell_coord(ri.y) + ((k / 3) % 3) - 1;
    int nz = cell_coord(ri.z) + (k % 3)     - 1;
    if ((unsigned)nx >= kNC || (unsigned)ny >= kNC || (unsigned)nz >= kNC)
        return;

    int cid = ((b * kNC + nx) * kNC + ny) * kNC + nz;
    int cnt = min(cellCnt[cid], kCap);
    const float4* cp = cells + (size_t)cid * kCap;

    float sum = 0.0f;
    for (int s = 0; s < cnt; ++s) {
        float4 c   = cp[s];
        float dot  = __fmaf_rn(ri.z, c.z,
                     __fmaf_rn(ri.y, c.y, __fmul_rn(ri.x, c.x)));
        float d2   = __fmaf_rn(-2.0f, dot, __fadd_rn(ri.w, c.w));
        float dist = fast_sqrt(__builtin_fabsf(d2));
        sum += (d2 <= 49.0f) ? dist : 0.0f;
    }
    if (sum != 0.0f) {
        atomicAdd(out + (size_t)i * 8 + 1, sum);
    }
}

// ---------------------------------------------------------------------------
// Fallback (ws too small): self-contained full nbr kernel with LDS staging.
// ---------------------------------------------------------------------------
__global__ __launch_bounds__(256)
void nbr_kernel_lds(const float* __restrict__ coords,
                    const int*   __restrict__ cidx,
                    float*       __restrict__ out)
{
    __shared__ float4 sc[kM];
    int b    = blockIdx.x >> 6;
    int row0 = (blockIdx.x & 63) << 6;
    for (int j = threadIdx.x; j < kM; j += 256) {
        int idx = cidx[b * kM + j];
        const float* s = coords + (size_t)(b * kM + idx) * 3;
        float x = s[0], y = s[1], z = s[2];
        sc[j] = make_float4(x, y, z, sq_np(x, y, z));
    }
    __syncthreads();
    int r   = row0 + (threadIdx.x >> 2);
    int sub = threadIdx.x & 3;
    float4 ci = sc[r];
    float sum = 0.0f;
    for (int jj = 0; jj < kM / 4; ++jj) {
        float4 c   = sc[4 * jj + sub];
        float dot  = __fmaf_rn(ci.z, c.z,
                     __fmaf_rn(ci.y, c.y, __fmul_rn(ci.x, c.x)));
        float d2   = __fmaf_rn(-2.0f, dot, __fadd_rn(ci.w, c.w));
        float dist = fast_sqrt(fmaxf(d2, 0.0f));
        sum += (d2 <= 49.0f) ? dist : 0.0f;
    }
    sum += __shfl_xor(sum, 1);
    sum += __shfl_xor(sum, 2);
    if (sub == 0)
        out[(size_t)(b * kM + r) * 8 + 1] = (ci.x != kPadF) ? sum : 0.0f;
}

// ---------------------------------------------------------------------------
extern "C" void kernel_launch(void* const* d_in, const int* in_sizes, int n_in,
                              void* d_out, int out_size, void* d_ws, size_t ws_size,
                              hipStream_t stream) {
    const float* coords   = (const float*)d_in[0];
    const int*   cidx     = (const int*)d_in[2];
    const int*   partners = (const int*)d_in[3];
    const int*   aidx     = (const int*)d_in[4];
    float*       out      = (float*)d_out;

    char*   wsB     = (char*)d_ws;
    float4* ws      = (float4*)(wsB + kOffWs);
    int*    cellCnt = (int*)(wsB + kOffCnt);
    float4* cells   = (float4*)(wsB + kOffCells);

    if (ws_size >= kWsNeeded) {
        // zero the cell counters (poisoned 0xAA before every timed launch)
        hipMemsetAsync(cellCnt, 0, (size_t)kB * kNC3 * sizeof(int), stream);
        hipLaunchKernelGGL(per_atom_kernel, dim3(kN / 64), dim3(64), 0, stream,
                           coords, cidx, partners, aidx, out, ws, cellCnt, cells);
        hipLaunchKernelGGL(nbr_cell_kernel, dim3((27 * kN) / 256), dim3(256),
                           0, stream, ws, cellCnt, cells, out);
    } else {
        // fallback: no scratch — LDS-staged full O(M^2) path
        hipLaunchKernelGGL(per_atom_kernel, dim3(kN / 64), dim3(64), 0, stream,
                           coords, cidx, partners, aidx, out,
                           (float4*)d_ws, (int*)d_ws, (float4*)d_ws);
        hipLaunchKernelGGL(nbr_kernel_lds, dim3(kB * 64), dim3(256), 0, stream,
                           coords, cidx, out);
    }
}

// Round 15
// 74.225 us; speedup vs baseline: 1.1140x; 1.0051x over previous
//
#include <hip/hip_runtime.h>
#include <math.h>

#define kB 4
#define kM 4096
#define kN (kB * kM)
#define kPadF -999.0f
#define kPadI -999

#define kNC   11                    // cells per axis; 80/11 = 7.27 > CUTOFF
#define kNC3  (kNC * kNC * kNC)     // 1331 cells per batch
#define kCap  64                    // atoms per cell (realistic max ~15)
// d_ws layout (bytes):
#define kOffWs     0                            // float4[kN]      = 256 KB
#define kOffCnt    262144                       // int[kB*kNC3]    = 21 KB
#define kOffCells  524288                       // float4[kB*kNC3*kCap] = 5.45 MB
#define kWsNeeded  (kOffCells + (size_t)kB * kNC3 * kCap * 16)

// numpy-mimicking squared norm: (x*x + y*y) + z*z, all round-to-nearest.
__device__ __forceinline__ float sq_np(float x, float y, float z) {
    return __fadd_rn(__fadd_rn(__fmul_rn(x, x), __fmul_rn(y, y)),
                     __fmul_rn(z, z));
}

// raw v_sqrt_f32 (<=1 ulp). Mask is decided by the exact d2<=49 compare.
__device__ __forceinline__ float fast_sqrt(float x) {
#if __has_builtin(__builtin_amdgcn_sqrtf)
    return __builtin_amdgcn_sqrtf(x);
#else
    float r;
    asm volatile("v_sqrt_f32 %0, %1" : "=v"(r) : "v"(x));
    return r;
#endif
}

__device__ __forceinline__ int cell_coord(float v) {
    int c = (int)(v * (11.0f / 80.0f));
    return min(c, kNC - 1);
}

// ---------------------------------------------------------------------------
// Kernel 1 (R15 role-split): 64K threads, 4 independent roles x 16K rows.
// role = blockIdx>>6 (wave-uniform). 4 waves/CU so the roles' latency
// chains hide each other (R14 had 1 wave/CU and a dependent atomic chain).
//   role 0: gather -> ws + cell-bin (atomic slot) + out col1 = 0
//   role 1: dihedral -> out col0
//   role 2: partner0 -> out cols 2,3,4
//   role 3: partner1 -> out cols 5,6,7
// Disjoint output columns -> no write conflicts.
// ---------------------------------------------------------------------------
__global__ __launch_bounds__(256)
void per_atom_kernel(const float* __restrict__ coords,   // (B,M,3)
                     const int*   __restrict__ cidx,     // (N,)
                     const int*   __restrict__ partners, // (N,2)
                     const int*   __restrict__ aidx,     // (N,4)
                     float*       __restrict__ out,      // (N,8)
                     float4*      __restrict__ ws,       // gathered rows
                     int*         __restrict__ cellCnt,  // (B*1331,) zeroed
                     float4*      __restrict__ cells)    // (B*1331*kCap,)
{
    int role = blockIdx.x >> 6;                 // 64 blocks per role
    int i    = ((blockIdx.x & 63) << 8) + threadIdx.x;   // 0..16383
    int b    = i >> 12;

    if (role == 0) {
        // ---- gather + bin + col1 init ----
        int gc = cidx[i];
        const float* s = coords + (size_t)(b * kM + gc) * 3;
        float x = s[0], y = s[1], z = s[2];
        float4 v = make_float4(x, y, z, sq_np(x, y, z));
        ws[i] = v;
        out[(size_t)i * 8 + 1] = 0.0f;
        if (x != kPadF) {
            int cid = ((b * kNC + cell_coord(x)) * kNC + cell_coord(y)) * kNC
                      + cell_coord(z);
            int slot = atomicAdd(&cellCnt[cid], 1);
            if (slot < kCap) cells[(size_t)cid * kCap + slot] = v;
        }
    } else if (role == 1) {
        // ---- dihedral -> col 0 ----
        int4 a = *reinterpret_cast<const int4*>(aidx + 4 * i);
        float ang = kPadF;
        if (a.x != kPadI && a.y != kPadI && a.z != kPadI && a.w != kPadI) {
            int ai[4] = {a.x, a.y, a.z, a.w};
            float P[4][3];
            #pragma unroll
            for (int k = 0; k < 4; ++k) {
                int g  = ai[k];
                int gb = g >> 12;
                int gc = cidx[g];
                const float* s = coords + (size_t)(gb * kM + gc) * 3;
                P[k][0] = s[0]; P[k][1] = s[1]; P[k][2] = s[2];
            }
            float b1x = P[1][0] - P[0][0], b1y = P[1][1] - P[0][1], b1z = P[1][2] - P[0][2];
            float b2x = P[2][0] - P[1][0], b2y = P[2][1] - P[1][1], b2z = P[2][2] - P[1][2];
            float b3x = P[3][0] - P[2][0], b3y = P[3][1] - P[2][1], b3z = P[3][2] - P[2][2];
            float n1x = b1y * b2z - b1z * b2y;
            float n1y = b1z * b2x - b1x * b2z;
            float n1z = b1x * b2y - b1y * b2x;
            float n2x = b2y * b3z - b2z * b3y;
            float n2y = b2z * b3x - b2x * b3z;
            float n2z = b2x * b3y - b2y * b3x;
            float nb2 = sqrtf(b2x * b2x + b2y * b2y + b2z * b2z) + 1e-12f;
            float inv = 1.0f / nb2;
            float ux = b2x * inv, uy = b2y * inv, uz = b2z * inv;
            float m1x = n1y * uz - n1z * uy;
            float m1y = n1z * ux - n1x * uz;
            float m1z = n1x * uy - n1y * ux;
            float x = n1x * n2x + n1y * n2y + n1z * n2z;
            float y = m1x * n2x + m1y * n2y + m1z * n2z;
            ang = atan2f(y, x);
        }
        out[(size_t)i * 8 + 0] = ang;
    } else if (role == 2) {
        // ---- partner 0 -> cols 2,3,4 ----
        float o2, o3, o4;
        int p0 = partners[2 * i + 0];
        if (p0 == kPadI) { o2 = o3 = o4 = kPadF; }
        else {
            const float* s = coords + (size_t)(b * kM + p0) * 3;
            o2 = s[0]; o3 = s[1]; o4 = s[2];
        }
        float* o = out + (size_t)i * 8;
        o[2] = o2; o[3] = o3; o[4] = o4;
    } else {
        // ---- partner 1 -> cols 5,6,7 ----
        float o5, o6, o7;
        int p1 = partners[2 * i + 1];
        if (p1 == kPadI) { o5 = o6 = o7 = kPadF; }
        else {
            const float* s = coords + (size_t)(b * kM + p1) * 3;
            o5 = s[0]; o6 = s[1]; o7 = s[2];
        }
        float* o = out + (size_t)i * 8;
        o[5] = o5; o[6] = o6; o[7] = o7;
    }
}

// ---------------------------------------------------------------------------
// Kernel 2: CELL-LIST nbr sums (col 1). Task = (row i, neighbor cell k).
// Included-pair set and per-pair numerics IDENTICAL to the passing R13/R14
// kernels (candidates beyond the 27-cell window have gram-d2 >= ~52.8 > 49).
// Pads never binned; pad rows return early.
// ---------------------------------------------------------------------------
__global__ __launch_bounds__(256)
void nbr_cell_kernel(const float4* __restrict__ ws,      // (N,) x,y,z,sq
                     const int*    __restrict__ cellCnt, // (B*1331,)
                     const float4* __restrict__ cells,   // (B*1331*kCap,)
                     float*        __restrict__ out)     // (N,8)
{
    int task = blockIdx.x * 256 + threadIdx.x;
    if (task >= 27 * kN) return;
    int k = task >> 14;            // 0..26  (kN = 16384 = 2^14)
    int i = task & (kN - 1);

    float4 ri = ws[i];
    if (ri.x == kPadF) return;

    int b  = i >> 12;
    int nx = cell_coord(ri.x) + (k / 9)       - 1;
    int ny = cell_coord(ri.y) + ((k / 3) % 3) - 1;
    int nz = cell_coord(ri.z) + (k % 3)       - 1;
    if ((unsigned)nx >= kNC || (unsigned)ny >= kNC || (unsigned)nz >= kNC)
        return;

    int cid = ((b * kNC + nx) * kNC + ny) * kNC + nz;
    int cnt = min(cellCnt[cid], kCap);
    const float4* cp = cells + (size_t)cid * kCap;

    float sum = 0.0f;
    for (int s = 0; s < cnt; ++s) {
        float4 c   = cp[s];
        float dot  = __fmaf_rn(ri.z, c.z,
                     __fmaf_rn(ri.y, c.y, __fmul_rn(ri.x, c.x)));
        float d2   = __fmaf_rn(-2.0f, dot, __fadd_rn(ri.w, c.w));
        float dist = fast_sqrt(__builtin_fabsf(d2));
        sum += (d2 <= 49.0f) ? dist : 0.0f;
    }
    if (sum != 0.0f) {
        atomicAdd(out + (size_t)i * 8 + 1, sum);
    }
}

// ---------------------------------------------------------------------------
// Fallbacks (ws too small): monolithic per-atom + LDS-staged O(M^2) nbr.
// ---------------------------------------------------------------------------
__global__ __launch_bounds__(64)
void per_atom_mono_kernel(const float* __restrict__ coords,
                          const int*   __restrict__ cidx,
                          const int*   __restrict__ partners,
                          const int*   __restrict__ aidx,
                          float*       __restrict__ out)
{
    int i = blockIdx.x * 64 + threadIdx.x;
    if (i >= kN) return;
    int b = i >> 12;

    float o2, o3, o4, o5, o6, o7;
    int p0 = partners[2 * i + 0];
    int p1 = partners[2 * i + 1];
    if (p0 == kPadI) { o2 = o3 = o4 = kPadF; }
    else {
        const float* s = coords + (size_t)(b * kM + p0) * 3;
        o2 = s[0]; o3 = s[1]; o4 = s[2];
    }
    if (p1 == kPadI) { o5 = o6 = o7 = kPadF; }
    else {
        const float* s = coords + (size_t)(b * kM + p1) * 3;
        o5 = s[0]; o6 = s[1]; o7 = s[2];
    }

    int4 a = *reinterpret_cast<const int4*>(aidx + 4 * i);
    float ang = kPadF;
    if (a.x != kPadI && a.y != kPadI && a.z != kPadI && a.w != kPadI) {
        int ai[4] = {a.x, a.y, a.z, a.w};
        float P[4][3];
        #pragma unroll
        for (int k = 0; k < 4; ++k) {
            int g  = ai[k];
            int gb = g >> 12;
            int gc = cidx[g];
            const float* s = coords + (size_t)(gb * kM + gc) * 3;
            P[k][0] = s[0]; P[k][1] = s[1]; P[k][2] = s[2];
        }
        float b1x = P[1][0] - P[0][0], b1y = P[1][1] - P[0][1], b1z = P[1][2] - P[0][2];
        float b2x = P[2][0] - P[1][0], b2y = P[2][1] - P[1][1], b2z = P[2][2] - P[1][2];
        float b3x = P[3][0] - P[2][0], b3y = P[3][1] - P[2][1], b3z = P[3][2] - P[2][2];
        float n1x = b1y * b2z - b1z * b2y;
        float n1y = b1z * b2x - b1x * b2z;
        float n1z = b1x * b2y - b1y * b2x;
        float n2x = b2y * b3z - b2z * b3y;
        float n2y = b2z * b3x - b2x * b3z;
        float n2z = b2x * b3y - b2y * b3x;
        float nb2 = sqrtf(b2x * b2x + b2y * b2y + b2z * b2z) + 1e-12f;
        float inv = 1.0f / nb2;
        float ux = b2x * inv, uy = b2y * inv, uz = b2z * inv;
        float m1x = n1y * uz - n1z * uy;
        float m1y = n1z * ux - n1x * uz;
        float m1z = n1x * uy - n1y * ux;
        float x = n1x * n2x + n1y * n2y + n1z * n2z;
        float y = m1x * n2x + m1y * n2y + m1z * n2z;
        ang = atan2f(y, x);
    }

    float4* o = reinterpret_cast<float4*>(out + (size_t)i * 8);
    o[0] = make_float4(ang, 0.0f, o2, o3);
    o[1] = make_float4(o4, o5, o6, o7);
}

__global__ __launch_bounds__(256)
void nbr_kernel_lds(const float* __restrict__ coords,
                    const int*   __restrict__ cidx,
                    float*       __restrict__ out)
{
    __shared__ float4 sc[kM];
    int b    = blockIdx.x >> 6;
    int row0 = (blockIdx.x & 63) << 6;
    for (int j = threadIdx.x; j < kM; j += 256) {
        int idx = cidx[b * kM + j];
        const float* s = coords + (size_t)(b * kM + idx) * 3;
        float x = s[0], y = s[1], z = s[2];
        sc[j] = make_float4(x, y, z, sq_np(x, y, z));
    }
    __syncthreads();
    int r   = row0 + (threadIdx.x >> 2);
    int sub = threadIdx.x & 3;
    float4 ci = sc[r];
    float sum = 0.0f;
    for (int jj = 0; jj < kM / 4; ++jj) {
        float4 c   = sc[4 * jj + sub];
        float dot  = __fmaf_rn(ci.z, c.z,
                     __fmaf_rn(ci.y, c.y, __fmul_rn(ci.x, c.x)));
        float d2   = __fmaf_rn(-2.0f, dot, __fadd_rn(ci.w, c.w));
        float dist = fast_sqrt(fmaxf(d2, 0.0f));
        sum += (d2 <= 49.0f) ? dist : 0.0f;
    }
    sum += __shfl_xor(sum, 1);
    sum += __shfl_xor(sum, 2);
    if (sub == 0)
        out[(size_t)(b * kM + r) * 8 + 1] = (ci.x != kPadF) ? sum : 0.0f;
}

// ---------------------------------------------------------------------------
extern "C" void kernel_launch(void* const* d_in, const int* in_sizes, int n_in,
                              void* d_out, int out_size, void* d_ws, size_t ws_size,
                              hipStream_t stream) {
    const float* coords   = (const float*)d_in[0];
    const int*   cidx     = (const int*)d_in[2];
    const int*   partners = (const int*)d_in[3];
    const int*   aidx     = (const int*)d_in[4];
    float*       out      = (float*)d_out;

    char*   wsB     = (char*)d_ws;
    float4* ws      = (float4*)(wsB + kOffWs);
    int*    cellCnt = (int*)(wsB + kOffCnt);
    float4* cells   = (float4*)(wsB + kOffCells);

    if (ws_size >= kWsNeeded) {
        hipMemsetAsync(cellCnt, 0, (size_t)kB * kNC3 * sizeof(int), stream);
        hipLaunchKernelGGL(per_atom_kernel, dim3(256), dim3(256), 0, stream,
                           coords, cidx, partners, aidx, out, ws, cellCnt, cells);
        hipLaunchKernelGGL(nbr_cell_kernel, dim3((27 * kN) / 256), dim3(256),
                           0, stream, ws, cellCnt, cells, out);
    } else {
        hipLaunchKernelGGL(per_atom_mono_kernel, dim3(kN / 64), dim3(64), 0, stream,
                           coords, cidx, partners, aidx, out);
        hipLaunchKernelGGL(nbr_kernel_lds, dim3(kB * 64), dim3(256), 0, stream,
                           coords, cidx, out);
    }
}